// Round 1
// baseline (2114.451 us; speedup 1.0000x reference)
//
#include <hip/hip_runtime.h>
#include <math.h>

// Problem constants
#define KD 4608          // k = 3*3*512
#define N0 512
#define WDECAY 0.0005f

// out offsets (floats)
#define OFF_E  0
#define OFF_S  16777216
#define OFF_L  19136512
#define OFF_HN 40370176
#define OFF_CN 40554496

__device__ __forceinline__ float sigf(float x){ return 1.0f/(1.0f+expf(-x)); }

// ---------------- new_e = e*(1-lr*wd) - lr*grad ----------------
__global__ __launch_bounds__(256) void new_e_kernel(
    float* __restrict__ out, const float* __restrict__ e,
    const float* __restrict__ g, const float* __restrict__ lrp)
{
  const float lr = lrp[0];
  const float a = 1.0f - lr * WDECAY;
  size_t i = ((size_t)blockIdx.x * 256 + threadIdx.x) * 4;
  float4 ev = *(const float4*)(e + i);
  float4 gv = *(const float4*)(g + i);
  float4 o;
  o.x = ev.x * a - lr * gv.x;
  o.y = ev.y * a - lr * gv.y;
  o.z = ev.z * a - lr * gv.z;
  o.w = ev.w * a - lr * gv.w;
  *(float4*)(out + i) = o;
}

// ---------------- transpose: dst[c][r] = src[r][c] * s ----------------
__global__ __launch_bounds__(256) void transpose_k(
    float* __restrict__ dst, const float* __restrict__ src,
    int R, int Cc, const float* scale_ptr, float scale_const)
{
  __shared__ float tile[32][33];
  float s = scale_const * (scale_ptr ? scale_ptr[0] : 1.0f);
  int c0 = blockIdx.x * 32, r0 = blockIdx.y * 32;
  int tx = threadIdx.x, ty = threadIdx.y;
#pragma unroll
  for (int i = 0; i < 32; i += 8)
    tile[ty + i][tx] = src[(size_t)(r0 + ty + i) * Cc + c0 + tx] * s;
  __syncthreads();
#pragma unroll
  for (int i = 0; i < 32; i += 8)
    dst[(size_t)(c0 + ty + i) * R + r0 + tx] = tile[tx][ty + i];
}

// ---------------- out(512x512) += X^T @ Y, split-K with atomics ----------------
// X, Y: (Ktot x 512) row-major; block: 64x64 tile, z = K-chunk
__global__ __launch_bounds__(256) void gemm_tn_splitk(
    float* __restrict__ out, const float* __restrict__ X,
    const float* __restrict__ Y, int Kchunk)
{
  __shared__ float Xs[16][64];
  __shared__ float Ys[16][64];
  const int tid = threadIdx.x;
  const int tx = tid & 15, ty = tid >> 4;
  const int a0 = blockIdx.x * 64, b0 = blockIdx.y * 64;
  const int k0 = blockIdx.z * Kchunk;
  const int lk = tid >> 4, lc = (tid & 15) << 2;
  float acc[4][4] = {};
  for (int kk = 0; kk < Kchunk; kk += 16){
    *(float4*)&Xs[lk][lc] = *(const float4*)&X[(size_t)(k0+kk+lk)*512 + a0 + lc];
    *(float4*)&Ys[lk][lc] = *(const float4*)&Y[(size_t)(k0+kk+lk)*512 + b0 + lc];
    __syncthreads();
#pragma unroll
    for (int k = 0; k < 16; ++k){
      float4 a4 = *(const float4*)&Xs[k][ty<<2];
      float4 b4 = *(const float4*)&Ys[k][tx<<2];
      float av[4] = {a4.x,a4.y,a4.z,a4.w};
      float bv[4] = {b4.x,b4.y,b4.z,b4.w};
#pragma unroll
      for (int i=0;i<4;i++)
#pragma unroll
        for (int j=0;j<4;j++)
          acc[i][j] += av[i]*bv[j];
    }
    __syncthreads();
  }
#pragma unroll
  for (int i=0;i<4;i++)
#pragma unroll
    for (int j=0;j<4;j++)
      atomicAdd(&out[(size_t)(a0+(ty<<2)+i)*512 + b0+(tx<<2)+j], acc[i][j]);
}

// ---------------- Asym = 0.5*(A + A^T), 512x512 ----------------
__global__ __launch_bounds__(256) void sym_kernel(
    float* __restrict__ out, const float* __restrict__ A)
{
  int idx = blockIdx.x * 256 + threadIdx.x;
  int a = idx >> 9, b = idx & 511;
  out[idx] = 0.5f * (A[idx] + A[b*512 + a]);
}

// ---------------- D = beta*C0 + alpha*(A @ Bm) ----------------
// A: (Mdim x K) row-major (lda), Bm: (K x 512) row-major, D/C0: (Mdim x 512)
// tile 64 x TN, 256 threads, micro 4 x (TN/16)
template<int TN>
__global__ __launch_bounds__(256) void gemm_nn(
    float* __restrict__ D, const float* __restrict__ A,
    const float* __restrict__ Bm, const float* __restrict__ C0,
    float alpha, float beta, int K, int lda)
{
  constexpr int WN = TN/16;
  __shared__ float As[16][64];
  __shared__ float Bs[16][TN];
  const int tid = threadIdx.x;
  const int tx = tid & 15, ty = tid >> 4;
  const int m0 = blockIdx.x * 64, n0 = blockIdx.y * TN;
  const int ar = tid >> 2, ak = (tid & 3) << 2;
  constexpr int BPR = TN/4;          // float4s per Bs row
  const int bk = tid / BPR;
  const int bn = (tid % BPR) << 2;
  constexpr int BP = (16*BPR)/256;   // passes (1 or 2)
  constexpr int BKSTEP = 256/BPR;
  float acc[4][WN];
#pragma unroll
  for (int i=0;i<4;i++)
#pragma unroll
    for (int j=0;j<WN;j++) acc[i][j]=0.f;

  for (int k0 = 0; k0 < K; k0 += 16){
    float4 av = *(const float4*)&A[(size_t)(m0+ar)*lda + k0 + ak];
    As[ak+0][ar]=av.x; As[ak+1][ar]=av.y; As[ak+2][ar]=av.z; As[ak+3][ar]=av.w;
#pragma unroll
    for (int p=0;p<BP;p++){
      int kk = bk + p*BKSTEP;
      *(float4*)&Bs[kk][bn] = *(const float4*)&Bm[(size_t)(k0+kk)*512 + n0 + bn];
    }
    __syncthreads();
#pragma unroll
    for (int k=0;k<16;k++){
      float4 a4 = *(const float4*)&As[k][ty<<2];
      float av2[4] = {a4.x,a4.y,a4.z,a4.w};
      float bv[WN];
#pragma unroll
      for (int j=0;j<WN;j+=4){
        float4 b4 = *(const float4*)&Bs[k][tx*WN + j];
        bv[j]=b4.x; bv[j+1]=b4.y; bv[j+2]=b4.z; bv[j+3]=b4.w;
      }
#pragma unroll
      for (int i=0;i<4;i++)
#pragma unroll
        for (int j=0;j<WN;j++)
          acc[i][j] += av2[i]*bv[j];
    }
    __syncthreads();
  }
#pragma unroll
  for (int i=0;i<4;i++){
    int r = m0 + (ty<<2) + i;
#pragma unroll
    for (int j=0;j<WN;j++){
      int c = n0 + tx*WN + j;
      float v = alpha * acc[i][j];
      if (C0) v += beta * C0[(size_t)r*512 + c];
      D[(size_t)r*512 + c] = v;
    }
  }
}

// ---------------- x[i] = clip(log(|rownorm2(G_i)|)/10, -1, 1) ----------------
__global__ __launch_bounds__(256) void rowsq_kernel(
    const float* __restrict__ G, float* __restrict__ x)
{
  int row = blockIdx.x * 4 + (threadIdx.x >> 6);
  int lane = threadIdx.x & 63;
  const float* g = G + (size_t)row * 512;
  float s = 0.f;
#pragma unroll
  for (int t = 0; t < 8; ++t){ float v = g[lane + t*64]; s += v*v; }
  for (int off = 32; off; off >>= 1) s += __shfl_down(s, off, 64);
  if (lane == 0){
    float v = logf(fabsf(s)) * 0.1f;   // /P_CONST
    x[row] = fminf(fmaxf(v, -1.f), 1.f);
  }
}

// ---------------- 2-layer LSTM, 1 timestep, batch 4608, H=20 ----------------
__global__ __launch_bounds__(256) void lstm_kernel(
    const float* __restrict__ x, const float* __restrict__ Lh,
    const float* __restrict__ Lc,
    const float* __restrict__ Wih0, const float* __restrict__ Whh0,
    const float* __restrict__ bih0, const float* __restrict__ bhh0,
    const float* __restrict__ Wih1, const float* __restrict__ Whh1,
    const float* __restrict__ bih1, const float* __restrict__ bhh1,
    const float* __restrict__ Wl, const float* __restrict__ bl,
    float* __restrict__ out_hn, float* __restrict__ out_cn,
    float* __restrict__ lp)
{
  __shared__ float sWih0[80], sWhh0[1600], sb0[80];
  __shared__ float sWih1[1600], sWhh1[1600], sb1[80];
  __shared__ float sWl[20], sbl;
  int tid = threadIdx.x;
  for (int t = tid; t < 80; t += 256){
    sWih0[t] = Wih0[t];
    sb0[t] = bih0[t] + bhh0[t];
    sb1[t] = bih1[t] + bhh1[t];
  }
  for (int t = tid; t < 1600; t += 256){
    sWhh0[t] = Whh0[t];
    sWih1[t] = Wih1[t];
    sWhh1[t] = Whh1[t];
  }
  if (tid < 20) sWl[tid] = Wl[tid];
  if (tid == 0) sbl = bl[0];
  __syncthreads();
  int b = blockIdx.x * 256 + tid;
  const float xv = x[b];
  float hp[20], h0n[20];
#pragma unroll
  for (int c = 0; c < 20; ++c) hp[c] = Lh[b*20 + c];
  // layer 0 (input dim 1); gate order i,f,g,o
#pragma unroll
  for (int c = 0; c < 20; ++c){
    float gi = xv * sWih0[c]      + sb0[c];
    float gf = xv * sWih0[20 + c] + sb0[20 + c];
    float gg = xv * sWih0[40 + c] + sb0[40 + c];
    float go = xv * sWih0[60 + c] + sb0[60 + c];
#pragma unroll
    for (int k = 0; k < 20; ++k){
      float h = hp[k];
      gi += h * sWhh0[c*20 + k];
      gf += h * sWhh0[(20 + c)*20 + k];
      gg += h * sWhh0[(40 + c)*20 + k];
      go += h * sWhh0[(60 + c)*20 + k];
    }
    float c0v = Lc[b*20 + c];
    float cn = sigf(gf) * c0v + sigf(gi) * tanhf(gg);
    float hn = sigf(go) * tanhf(cn);
    out_hn[b*20 + c] = hn;
    out_cn[b*20 + c] = cn;
    h0n[c] = hn;
  }
  // layer 1 (input = h0n)
  float hp1[20];
#pragma unroll
  for (int c = 0; c < 20; ++c) hp1[c] = Lh[92160 + b*20 + c];
  float lacc = sbl;
#pragma unroll
  for (int c = 0; c < 20; ++c){
    float gi = sb1[c], gf = sb1[20+c], gg = sb1[40+c], go = sb1[60+c];
#pragma unroll
    for (int k = 0; k < 20; ++k){
      float a0 = h0n[k], a1 = hp1[k];
      gi += a0 * sWih1[c*20 + k]      + a1 * sWhh1[c*20 + k];
      gf += a0 * sWih1[(20+c)*20 + k] + a1 * sWhh1[(20+c)*20 + k];
      gg += a0 * sWih1[(40+c)*20 + k] + a1 * sWhh1[(40+c)*20 + k];
      go += a0 * sWih1[(60+c)*20 + k] + a1 * sWhh1[(60+c)*20 + k];
    }
    float c0v = Lc[92160 + b*20 + c];
    float cn = sigf(gf) * c0v + sigf(gi) * tanhf(gg);
    float hn = sigf(go) * tanhf(cn);
    out_hn[92160 + b*20 + c] = hn;
    out_cn[92160 + b*20 + c] = cn;
    lacc += hn * sWl[c];
  }
  lp[b] = lacc * 0.1f;   // * SCALE
}

// ---------------- mean of lp (4608) ----------------
__global__ __launch_bounds__(256) void mean_kernel(
    const float* __restrict__ lp, float* __restrict__ meanout)
{
  __shared__ float red[4];
  int tid = threadIdx.x;
  float s = 0.f;
  for (int i = tid; i < KD; i += 256) s += lp[i];
  for (int off = 32; off; off >>= 1) s += __shfl_down(s, off, 64);
  if ((tid & 63) == 0) red[tid >> 6] = s;
  __syncthreads();
  if (tid == 0) meanout[0] = (red[0]+red[1]+red[2]+red[3]) * (1.0f/4608.0f);
}

// ---------------- L[i][j] = max(Lb[i][j], (i==j)? l_i : 0) ----------------
__global__ __launch_bounds__(256) void build_L_kernel(
    float* __restrict__ outL, const float* __restrict__ Lb,
    const float* __restrict__ lp, const float* __restrict__ meanp)
{
  size_t idx = (size_t)blockIdx.x * 256 + threadIdx.x;   // float4 index
  int i = (int)(idx / 1152);
  int j = (int)(idx % 1152) * 4;
  float li = lp[i] - meanp[0] + 1.0f;
  float4 lb = *(const float4*)&Lb[(size_t)i*KD + j];
  float4 o;
  o.x = fmaxf(lb.x, (j+0 == i) ? li : 0.f);
  o.y = fmaxf(lb.y, (j+1 == i) ? li : 0.f);
  o.z = fmaxf(lb.z, (j+2 == i) ? li : 0.f);
  o.w = fmaxf(lb.w, (j+3 == i) ? li : 0.f);
  *(float4*)&outL[(size_t)i*KD + j] = o;
}

// ---------------- B += M (elementwise, float4) ----------------
__global__ __launch_bounds__(256) void add_kernel(
    float* __restrict__ B, const float* __restrict__ M)
{
  size_t i = ((size_t)blockIdx.x * 256 + threadIdx.x) * 4;
  float4 b = *(const float4*)(B + i);
  float4 m = *(const float4*)(M + i);
  b.x += m.x; b.y += m.y; b.z += m.z; b.w += m.w;
  *(float4*)(B + i) = b;
}

// ---------------- Cholesky: factor 64x64 diag block + invert it ----------------
__global__ __launch_bounds__(256) void chol_factor(
    float* __restrict__ C, float* __restrict__ invLg, int kb)
{
  __shared__ float T[64][65];
  __shared__ float W[64][65];
  const int tid = threadIdx.x;
  const int base = kb * 64;
  for (int t = tid; t < 4096; t += 256)
    T[t>>6][t&63] = C[(size_t)(base + (t>>6))*512 + base + (t&63)];
  __syncthreads();
  const int i = tid & 63, q = tid >> 6;
  for (int j = 0; j < 64; ++j){
    float dj = sqrtf(T[j][j]);
    __syncthreads();
    if (q == 0){
      if (i == j) T[j][j] = dj;
      else if (i > j) T[i][j] /= dj;
    }
    __syncthreads();
    if (i > j){
      float lij = T[i][j];
      for (int jj = j+1+q; jj <= i; jj += 4)
        T[i][jj] -= lij * T[jj][j];
    }
    __syncthreads();
  }
  // forward-substitution inverse of lower-tri T (column per thread)
  if (q == 0){
    const int j = i;
    for (int r = 0; r < j; ++r) W[r][j] = 0.f;
    W[j][j] = 1.0f / T[j][j];
    for (int r = j+1; r < 64; ++r){
      float ssum = 0.f;
      for (int k = j; k < r; ++k) ssum += T[r][k] * W[k][j];
      W[r][j] = -ssum / T[r][r];
    }
  }
  __syncthreads();
  for (int t = tid; t < 4096; t += 256){
    int r = t >> 6, c = t & 63;
    C[(size_t)(base + r)*512 + base + c] = T[r][c];
    invLg[kb*4096 + t] = W[r][c];
  }
}

// ---------------- panel solve: L21 = C21 @ invL^T (in-place) ----------------
__global__ __launch_bounds__(256) void chol_trsm(
    float* __restrict__ C, const float* __restrict__ invLg, int kb)
{
  __shared__ float Ts[64][65];
  __shared__ float Ws[64][65];
  const int tid = threadIdx.x;
  const int r0 = 64*(kb+1) + blockIdx.x * 64;
  const int cb = kb * 64;
  for (int t = tid; t < 1024; t += 256){
    int r = t >> 4, qd = (t & 15) << 2;
    float4 v = *(const float4*)&C[(size_t)(r0+r)*512 + cb + qd];
    Ts[r][qd]=v.x; Ts[r][qd+1]=v.y; Ts[r][qd+2]=v.z; Ts[r][qd+3]=v.w;
    float4 w = *(const float4*)&invLg[kb*4096 + r*64 + qd];
    Ws[r][qd]=w.x; Ws[r][qd+1]=w.y; Ws[r][qd+2]=w.z; Ws[r][qd+3]=w.w;
  }
  __syncthreads();
  const int tx = tid & 15, ty = tid >> 4;
  float acc[4][4] = {};
#pragma unroll 8
  for (int k = 0; k < 64; ++k){
    float a_[4], b_[4];
#pragma unroll
    for (int i=0;i<4;i++){ a_[i] = Ts[(ty<<2)+i][k]; b_[i] = Ws[(tx<<2)+i][k]; }
#pragma unroll
    for (int i=0;i<4;i++)
#pragma unroll
      for (int j=0;j<4;j++)
        acc[i][j] += a_[i]*b_[j];
  }
#pragma unroll
  for (int i=0;i<4;i++)
#pragma unroll
    for (int j=0;j<4;j++)
      C[(size_t)(r0+(ty<<2)+i)*512 + cb + (tx<<2)+j] = acc[i][j];
}

// ---------------- trailing update: C22 -= Lp @ Lp^T (lower tiles only) ------
__global__ __launch_bounds__(256) void chol_syrk(float* __restrict__ C, int kb)
{
  if (blockIdx.y > blockIdx.x) return;
  __shared__ float Ar[64][65];
  __shared__ float Ac[64][65];
  const int tid = threadIdx.x;
  const int base = 64*(kb+1);
  const int r0 = base + blockIdx.x * 64, c0 = base + blockIdx.y * 64;
  const int cb = kb * 64;
  for (int t = tid; t < 1024; t += 256){
    int r = t >> 4, qd = (t & 15) << 2;
    float4 v = *(const float4*)&C[(size_t)(r0+r)*512 + cb + qd];
    Ar[r][qd]=v.x; Ar[r][qd+1]=v.y; Ar[r][qd+2]=v.z; Ar[r][qd+3]=v.w;
    float4 w = *(const float4*)&C[(size_t)(c0+r)*512 + cb + qd];
    Ac[r][qd]=w.x; Ac[r][qd+1]=w.y; Ac[r][qd+2]=w.z; Ac[r][qd+3]=w.w;
  }
  __syncthreads();
  const int tx = tid & 15, ty = tid >> 4;
  float acc[4][4] = {};
#pragma unroll 8
  for (int k = 0; k < 64; ++k){
    float a_[4], b_[4];
#pragma unroll
    for (int i=0;i<4;i++){ a_[i] = Ar[(ty<<2)+i][k]; b_[i] = Ac[(tx<<2)+i][k]; }
#pragma unroll
    for (int i=0;i<4;i++)
#pragma unroll
      for (int j=0;j<4;j++)
        acc[i][j] += a_[i]*b_[j];
  }
#pragma unroll
  for (int i=0;i<4;i++)
#pragma unroll
    for (int j=0;j<4;j++){
      size_t o = (size_t)(r0+(ty<<2)+i)*512 + c0 + (tx<<2)+j;
      C[o] -= acc[i][j];
    }
}

// ---------------- Q panel: Q[:,jb] = (B[:,jb] - Q[:,:64jb] @ R[:,jb]) @ invR_jj
// R[k][col] = Lc[col][k] (strictly lower of C);  invR_jj = invL_jb^T
__global__ __launch_bounds__(256) void panel_q(
    float* __restrict__ Q, const float* __restrict__ B,
    const float* __restrict__ Lc, const float* __restrict__ invLg, int jb)
{
  __shared__ float Qs[16][64];
  __shared__ float Rs[16][68];
  __shared__ float Ts[64][65];
  __shared__ float Ws[64][65];
  const int tid = threadIdx.x;
  const int tx = tid & 15, ty = tid >> 4;
  const int r0 = blockIdx.x * 64;
  const int cb = jb * 64;
  for (int t = tid; t < 4096; t += 256)
    Ws[t>>6][t&63] = invLg[jb*4096 + t];
  float acc[4][4] = {};
  const int lr = tid >> 2, lk = (tid & 3) << 2;
  for (int k0 = 0; k0 < cb; k0 += 16){
    float4 qv = *(const float4*)&Q[(size_t)(r0+lr)*512 + k0 + lk];
    Qs[lk+0][lr]=qv.x; Qs[lk+1][lr]=qv.y; Qs[lk+2][lr]=qv.z; Qs[lk+3][lr]=qv.w;
    float4 rv = *(const float4*)&Lc[(size_t)(cb+lr)*512 + k0 + lk];
    Rs[lk+0][lr]=rv.x; Rs[lk+1][lr]=rv.y; Rs[lk+2][lr]=rv.z; Rs[lk+3][lr]=rv.w;
    __syncthreads();
#pragma unroll
    for (int k = 0; k < 16; ++k){
      float4 a4 = *(const float4*)&Qs[k][ty<<2];
      float av[4] = {a4.x,a4.y,a4.z,a4.w};
      float bv[4];
#pragma unroll
      for (int j=0;j<4;j++) bv[j] = Rs[k][(tx<<2)+j];
#pragma unroll
      for (int i=0;i<4;i++)
#pragma unroll
        for (int j=0;j<4;j++)
          acc[i][j] += av[i]*bv[j];
    }
    __syncthreads();
  }
  // Ts = B - Q@R
#pragma unroll
  for (int i=0;i<4;i++){
    int r = (ty<<2)+i;
#pragma unroll
    for (int j=0;j<4;j++){
      int c = (tx<<2)+j;
      Ts[r][c] = B[(size_t)(r0+r)*512 + cb + c] - acc[i][j];
    }
  }
  __syncthreads();
  float acc2[4][4] = {};
#pragma unroll 8
  for (int k = 0; k < 64; ++k){
    float a_[4], b_[4];
#pragma unroll
    for (int i=0;i<4;i++){ a_[i] = Ts[(ty<<2)+i][k]; b_[i] = Ws[(tx<<2)+i][k]; }
#pragma unroll
    for (int i=0;i<4;i++)
#pragma unroll
      for (int j=0;j<4;j++)
        acc2[i][j] += a_[i]*b_[j];
  }
#pragma unroll
  for (int i=0;i<4;i++)
#pragma unroll
    for (int j=0;j<4;j++)
      Q[(size_t)(r0+(ty<<2)+i)*512 + cb + (tx<<2)+j] = acc2[i][j];
}

extern "C" void kernel_launch(void* const* d_in, const int* in_sizes, int n_in,
                              void* d_out, int out_size, void* d_ws, size_t ws_size,
                              hipStream_t stream) {
  const float* e      = (const float*)d_in[0];
  const float* e_grad = (const float*)d_in[1];
  const float* s      = (const float*)d_in[2];
  const float* s_grad = (const float*)d_in[3];
  const float* L_h0   = (const float*)d_in[4];
  const float* L_c0   = (const float*)d_in[5];
  const float* L_before = (const float*)d_in[6];
  const float* W_ih0  = (const float*)d_in[7];
  const float* W_hh0  = (const float*)d_in[8];
  const float* b_ih0  = (const float*)d_in[9];
  const float* b_hh0  = (const float*)d_in[10];
  const float* W_ih1  = (const float*)d_in[11];
  const float* W_hh1  = (const float*)d_in[12];
  const float* b_ih1  = (const float*)d_in[13];
  const float* b_hh1  = (const float*)d_in[14];
  const float* Wl     = (const float*)d_in[15];
  const float* bl     = (const float*)d_in[16];
  const float* e_lr   = (const float*)d_in[17];
  const float* s_lr   = (const float*)d_in[18];

  float* out = (float*)d_out;
  float* out_e  = out + OFF_E;
  float* out_s  = out + OFF_S;
  float* out_L  = out + OFF_L;
  float* out_hn = out + OFF_HN;
  float* out_cn = out + OFF_CN;

  // workspace layout (floats); total ~31.6 MB
  float* ws   = (float*)d_ws;
  float* M    = ws;                 // (4608x512)  M = s^T
  float* Bb   = ws + 2359296;       // Mg -> LG -> B
  float* G    = ws + 4718592;       // G -> Q
  float* Abuf = ws + 7077888;       // A / A2
  float* Asym = ws + 7340032;
  float* Cb   = ws + 7602176;       // B^T B -> Cholesky factor (lower)
  float* invL = ws + 7864320;       // 8 x 64x64 inverse diag blocks
  float* xb   = ws + 7897088;
  float* lp   = ws + 7901696;
  float* meanb= ws + 7906304;

  // 1. new_e
  new_e_kernel<<<16384, 256, 0, stream>>>(out_e, e, e_grad, e_lr);
  // 2. M = s^T ; Mg = -s_lr * s_grad^T
  transpose_k<<<dim3(144,16), dim3(32,8), 0, stream>>>(M, s, 512, KD, nullptr, 1.0f);
  transpose_k<<<dim3(144,16), dim3(32,8), 0, stream>>>(Bb, s_grad, 512, KD, s_lr, -1.0f);
  // 3. A = M^T Mg ; Asym
  hipMemsetAsync(Abuf, 0, 262144*sizeof(float), stream);
  gemm_tn_splitk<<<dim3(8,8,9), 256, 0, stream>>>(Abuf, M, Bb, 512);
  sym_kernel<<<1024, 256, 0, stream>>>(Asym, Abuf);
  // 4. G = Mg - M @ Asym
  gemm_nn<64><<<dim3(72,8), 256, 0, stream>>>(G, M, Asym, Bb, -1.f, 1.f, 512, 512);
  // 5. x = clip(log(|rownorm2|)/10, -1, 1)
  rowsq_kernel<<<1152, 256, 0, stream>>>(G, xb);
  // 6. LSTM (writes hn/cn outputs + pre-mean l)
  lstm_kernel<<<18, 256, 0, stream>>>(xb, L_h0, L_c0, W_ih0, W_hh0, b_ih0, b_hh0,
                                      W_ih1, W_hh1, b_ih1, b_hh1, Wl, bl,
                                      out_hn, out_cn, lp);
  mean_kernel<<<1, 256, 0, stream>>>(lp, meanb);
  // 7. L = max(diag(l), L_before)  (output)
  build_L_kernel<<<20736, 256, 0, stream>>>(out_L, L_before, lp, meanb);
  // 8. LG = L @ G   (the big 21.7 GF GEMM)
  gemm_nn<128><<<dim3(72,4), 256, 0, stream>>>(Bb, out_L, G, nullptr, 1.f, 0.f, KD, KD);
  // 9. A2 = M^T LG ; A2sym
  hipMemsetAsync(Abuf, 0, 262144*sizeof(float), stream);
  gemm_tn_splitk<<<dim3(8,8,9), 256, 0, stream>>>(Abuf, M, Bb, 512);
  sym_kernel<<<1024, 256, 0, stream>>>(Asym, Abuf);
  // 10. B = M + LG - M @ A2sym   (in-place on LG buffer)
  add_kernel<<<2304, 256, 0, stream>>>(Bb, M);
  gemm_nn<64><<<dim3(72,8), 256, 0, stream>>>(Bb, M, Asym, Bb, -1.f, 1.f, 512, 512);
  // 11. C = B^T B
  hipMemsetAsync(Cb, 0, 262144*sizeof(float), stream);
  gemm_tn_splitk<<<dim3(8,8,9), 256, 0, stream>>>(Cb, Bb, Bb, 512);
  // 12. blocked Cholesky C = Lc Lc^T (NB=64)
  for (int kb = 0; kb < 8; ++kb){
    chol_factor<<<1, 256, 0, stream>>>(Cb, invL, kb);
    int rem = 7 - kb;
    if (rem > 0){
      chol_trsm<<<rem, 256, 0, stream>>>(Cb, invL, kb);
      chol_syrk<<<dim3(rem, rem), 256, 0, stream>>>(Cb, kb);
    }
  }
  // 13. Q = B R^{-1} via block back-substitution (Q into G buffer);
  //     chol diag(R)>0 so the reference's sign fix is identity.
  for (int jb = 0; jb < 8; ++jb)
    panel_q<<<72, 256, 0, stream>>>(G, Bb, Cb, invL, jb);
  // 14. new_s = Q^T
  transpose_k<<<dim3(16,144), dim3(32,8), 0, stream>>>(out_s, G, KD, 512, nullptr, 1.0f);
}

// Round 2
// 1720.334 us; speedup vs baseline: 1.2291x; 1.2291x over previous
//
#include <hip/hip_runtime.h>
#include <math.h>

// Problem constants
#define KD 4608          // k = 3*3*512
#define N0 512
#define WDECAY 0.0005f

// out offsets (floats)
#define OFF_E  0
#define OFF_S  16777216
#define OFF_L  19136512
#define OFF_HN 40370176
#define OFF_CN 40554496

typedef unsigned short ushort_t;
typedef __attribute__((ext_vector_type(8))) short bf16x8;
typedef __attribute__((ext_vector_type(4))) float f32x4;

__device__ __forceinline__ float sigf(float x){ return 1.0f/(1.0f+expf(-x)); }

__device__ __forceinline__ unsigned short cvt_bf16(float x){
  unsigned int u = __float_as_uint(x);
  unsigned int r = (u + 0x7FFFu + ((u >> 16) & 1u)) >> 16;
  return (unsigned short)r;
}

__device__ __forceinline__ void gload_lds16(const void* g, void* l){
  __builtin_amdgcn_global_load_lds(
      (const __attribute__((address_space(1))) unsigned int*)g,
      (__attribute__((address_space(3))) unsigned int*)l, 16, 0, 0);
}

// ---------------- new_e = e*(1-lr*wd) - lr*grad ----------------
__global__ __launch_bounds__(256) void new_e_kernel(
    float* __restrict__ out, const float* __restrict__ e,
    const float* __restrict__ g, const float* __restrict__ lrp)
{
  const float lr = lrp[0];
  const float a = 1.0f - lr * WDECAY;
  size_t i = ((size_t)blockIdx.x * 256 + threadIdx.x) * 4;
  float4 ev = *(const float4*)(e + i);
  float4 gv = *(const float4*)(g + i);
  float4 o;
  o.x = ev.x * a - lr * gv.x;
  o.y = ev.y * a - lr * gv.y;
  o.z = ev.z * a - lr * gv.z;
  o.w = ev.w * a - lr * gv.w;
  *(float4*)(out + i) = o;
}

// ---------------- transpose: dst[c][r] = src[r][c] * s ----------------
__global__ __launch_bounds__(256) void transpose_k(
    float* __restrict__ dst, const float* __restrict__ src,
    int R, int Cc, const float* scale_ptr, float scale_const)
{
  __shared__ float tile[32][33];
  float s = scale_const * (scale_ptr ? scale_ptr[0] : 1.0f);
  int c0 = blockIdx.x * 32, r0 = blockIdx.y * 32;
  int tx = threadIdx.x, ty = threadIdx.y;
#pragma unroll
  for (int i = 0; i < 32; i += 8)
    tile[ty + i][tx] = src[(size_t)(r0 + ty + i) * Cc + c0 + tx] * s;
  __syncthreads();
#pragma unroll
  for (int i = 0; i < 32; i += 8)
    dst[(size_t)(c0 + ty + i) * R + r0 + tx] = tile[tx][ty + i];
}

// ---------------- transpose+convert: dst_bf16[c][r] = src[r][c] ----------------
__global__ __launch_bounds__(256) void transpose_cvt_bf16(
    ushort_t* __restrict__ dst, const float* __restrict__ src, int R, int Cc)
{
  __shared__ float tile[32][33];
  int c0 = blockIdx.x * 32, r0 = blockIdx.y * 32;
  int tx = threadIdx.x, ty = threadIdx.y;
#pragma unroll
  for (int i = 0; i < 32; i += 8)
    tile[ty + i][tx] = src[(size_t)(r0 + ty + i) * Cc + c0 + tx];
  __syncthreads();
#pragma unroll
  for (int i = 0; i < 32; i += 8)
    dst[(size_t)(c0 + ty + i) * R + r0 + tx] = cvt_bf16(tile[tx][ty + i]);
}

// ---------------- out(512x512) += X^T @ Y, split-K with atomics ----------------
__global__ __launch_bounds__(256) void gemm_tn_splitk(
    float* __restrict__ out, const float* __restrict__ X,
    const float* __restrict__ Y, int Kchunk)
{
  __shared__ float Xs[16][64];
  __shared__ float Ys[16][64];
  const int tid = threadIdx.x;
  const int tx = tid & 15, ty = tid >> 4;
  const int a0 = blockIdx.x * 64, b0 = blockIdx.y * 64;
  const int k0 = blockIdx.z * Kchunk;
  const int lk = tid >> 4, lc = (tid & 15) << 2;
  float acc[4][4] = {};
  for (int kk = 0; kk < Kchunk; kk += 16){
    *(float4*)&Xs[lk][lc] = *(const float4*)&X[(size_t)(k0+kk+lk)*512 + a0 + lc];
    *(float4*)&Ys[lk][lc] = *(const float4*)&Y[(size_t)(k0+kk+lk)*512 + b0 + lc];
    __syncthreads();
#pragma unroll
    for (int k = 0; k < 16; ++k){
      float4 a4 = *(const float4*)&Xs[k][ty<<2];
      float4 b4 = *(const float4*)&Ys[k][tx<<2];
      float av[4] = {a4.x,a4.y,a4.z,a4.w};
      float bv[4] = {b4.x,b4.y,b4.z,b4.w};
#pragma unroll
      for (int i=0;i<4;i++)
#pragma unroll
        for (int j=0;j<4;j++)
          acc[i][j] += av[i]*bv[j];
    }
    __syncthreads();
  }
#pragma unroll
  for (int i=0;i<4;i++)
#pragma unroll
    for (int j=0;j<4;j++)
      atomicAdd(&out[(size_t)(a0+(ty<<2)+i)*512 + b0+(tx<<2)+j], acc[i][j]);
}

// ---------------- Asym = 0.5*(A + A^T), 512x512 ----------------
__global__ __launch_bounds__(256) void sym_kernel(
    float* __restrict__ out, const float* __restrict__ A)
{
  int idx = blockIdx.x * 256 + threadIdx.x;
  int a = idx >> 9, b = idx & 511;
  out[idx] = 0.5f * (A[idx] + A[b*512 + a]);
}

// ---------------- D = beta*C0 + alpha*(A @ Bm) ----------------
template<int TN>
__global__ __launch_bounds__(256) void gemm_nn(
    float* __restrict__ D, const float* __restrict__ A,
    const float* __restrict__ Bm, const float* __restrict__ C0,
    float alpha, float beta, int K, int lda)
{
  constexpr int WN = TN/16;
  __shared__ float As[16][64];
  __shared__ float Bs[16][TN];
  const int tid = threadIdx.x;
  const int tx = tid & 15, ty = tid >> 4;
  const int m0 = blockIdx.x * 64, n0 = blockIdx.y * TN;
  const int ar = tid >> 2, ak = (tid & 3) << 2;
  constexpr int BPR = TN/4;
  const int bk = tid / BPR;
  const int bn = (tid % BPR) << 2;
  constexpr int BP = (16*BPR)/256;
  constexpr int BKSTEP = 256/BPR;
  float acc[4][WN];
#pragma unroll
  for (int i=0;i<4;i++)
#pragma unroll
    for (int j=0;j<WN;j++) acc[i][j]=0.f;

  for (int k0 = 0; k0 < K; k0 += 16){
    float4 av = *(const float4*)&A[(size_t)(m0+ar)*lda + k0 + ak];
    As[ak+0][ar]=av.x; As[ak+1][ar]=av.y; As[ak+2][ar]=av.z; As[ak+3][ar]=av.w;
#pragma unroll
    for (int p=0;p<BP;p++){
      int kk = bk + p*BKSTEP;
      *(float4*)&Bs[kk][bn] = *(const float4*)&Bm[(size_t)(k0+kk)*512 + n0 + bn];
    }
    __syncthreads();
#pragma unroll
    for (int k=0;k<16;k++){
      float4 a4 = *(const float4*)&As[k][ty<<2];
      float av2[4] = {a4.x,a4.y,a4.z,a4.w};
      float bv[WN];
#pragma unroll
      for (int j=0;j<WN;j+=4){
        float4 b4 = *(const float4*)&Bs[k][tx*WN + j];
        bv[j]=b4.x; bv[j+1]=b4.y; bv[j+2]=b4.z; bv[j+3]=b4.w;
      }
#pragma unroll
      for (int i=0;i<4;i++)
#pragma unroll
        for (int j=0;j<WN;j++)
          acc[i][j] += av2[i]*bv[j];
    }
    __syncthreads();
  }
#pragma unroll
  for (int i=0;i<4;i++){
    int r = m0 + (ty<<2) + i;
#pragma unroll
    for (int j=0;j<WN;j++){
      int c = n0 + tx*WN + j;
      float v = alpha * acc[i][j];
      if (C0) v += beta * C0[(size_t)r*512 + c];
      D[(size_t)r*512 + c] = v;
    }
  }
}

// ---------------- MFMA GEMM: C(4608x512 f32) = Lbf(4608x4608 bf16) @ G ----
// A-operand: Lbf row-major; B-operand: Gt (512x4608 bf16, row-major = G^T)
// 64x64 tile, BK=32, 4 waves (one 16-col slice each), 16x16x32 MFMA.
__global__ __launch_bounds__(256) void gemm_LG_mfma(
    float* __restrict__ C, const ushort_t* __restrict__ Lb,
    const ushort_t* __restrict__ Gt)
{
  __shared__ ushort_t As[64*32];
  __shared__ ushort_t Bs[64*32];
  const int id = blockIdx.x;
  // XCD swizzle: all 8 nb-blocks of one mb land on the same XCD (id % 8 fixed)
  const int mb = (id & 7) + 8 * (id >> 6);
  const int nb = (id >> 3) & 7;
  const int tid = threadIdx.x;
  const int w = tid >> 6, lane = tid & 63;
  const int m0 = mb * 64, n0 = nb * 64;
  f32x4 acc[4] = {};
  // staging: 256 chunks of 16B per tile; chunk tid -> row tid>>2, 16B-chunk tid&3
  const ushort_t* gA = Lb + (size_t)(m0 + (tid >> 2)) * KD + (tid & 3) * 8;
  const ushort_t* gB = Gt + (size_t)(n0 + (tid >> 2)) * KD + (tid & 3) * 8;
  ushort_t* lA = As + tid * 8;
  ushort_t* lB = Bs + tid * 8;
  const int mrow = lane & 15, kq = lane >> 4;
  const int aoff = mrow * 32 + kq * 8;
  for (int k0 = 0; k0 < KD; k0 += 32){
    gload_lds16(gA + k0, lA);
    gload_lds16(gB + k0, lB);
    __syncthreads();
    bf16x8 bfrag = *(const bf16x8*)&Bs[w * 16 * 32 + aoff];
#pragma unroll
    for (int mt = 0; mt < 4; ++mt){
      bf16x8 afrag = *(const bf16x8*)&As[mt * 16 * 32 + aoff];
      acc[mt] = __builtin_amdgcn_mfma_f32_16x16x32_bf16(afrag, bfrag, acc[mt], 0, 0, 0);
    }
    __syncthreads();
  }
  // C/D layout: col = lane&15, row = (lane>>4)*4 + reg
#pragma unroll
  for (int mt = 0; mt < 4; ++mt)
#pragma unroll
    for (int r = 0; r < 4; ++r)
      C[(size_t)(m0 + mt*16 + kq*4 + r) * 512 + n0 + w*16 + mrow] = acc[mt][r];
}

// ---------------- x[i] = clip(log(|rownorm2(G_i)|)/10, -1, 1) ----------------
__global__ __launch_bounds__(256) void rowsq_kernel(
    const float* __restrict__ G, float* __restrict__ x)
{
  int row = blockIdx.x * 4 + (threadIdx.x >> 6);
  int lane = threadIdx.x & 63;
  const float* g = G + (size_t)row * 512;
  float s = 0.f;
#pragma unroll
  for (int t = 0; t < 8; ++t){ float v = g[lane + t*64]; s += v*v; }
  for (int off = 32; off; off >>= 1) s += __shfl_down(s, off, 64);
  if (lane == 0){
    float v = logf(fabsf(s)) * 0.1f;
    x[row] = fminf(fmaxf(v, -1.f), 1.f);
  }
}

// ---------------- 2-layer LSTM, 1 timestep, batch 4608, H=20 ----------------
__global__ __launch_bounds__(256) void lstm_kernel(
    const float* __restrict__ x, const float* __restrict__ Lh,
    const float* __restrict__ Lc,
    const float* __restrict__ Wih0, const float* __restrict__ Whh0,
    const float* __restrict__ bih0, const float* __restrict__ bhh0,
    const float* __restrict__ Wih1, const float* __restrict__ Whh1,
    const float* __restrict__ bih1, const float* __restrict__ bhh1,
    const float* __restrict__ Wl, const float* __restrict__ bl,
    float* __restrict__ out_hn, float* __restrict__ out_cn,
    float* __restrict__ lp)
{
  __shared__ float sWih0[80], sWhh0[1600], sb0[80];
  __shared__ float sWih1[1600], sWhh1[1600], sb1[80];
  __shared__ float sWl[20], sbl;
  int tid = threadIdx.x;
  for (int t = tid; t < 80; t += 256){
    sWih0[t] = Wih0[t];
    sb0[t] = bih0[t] + bhh0[t];
    sb1[t] = bih1[t] + bhh1[t];
  }
  for (int t = tid; t < 1600; t += 256){
    sWhh0[t] = Whh0[t];
    sWih1[t] = Wih1[t];
    sWhh1[t] = Whh1[t];
  }
  if (tid < 20) sWl[tid] = Wl[tid];
  if (tid == 0) sbl = bl[0];
  __syncthreads();
  int b = blockIdx.x * 256 + tid;
  const float xv = x[b];
  float hp[20], h0n[20];
#pragma unroll
  for (int c = 0; c < 20; ++c) hp[c] = Lh[b*20 + c];
#pragma unroll
  for (int c = 0; c < 20; ++c){
    float gi = xv * sWih0[c]      + sb0[c];
    float gf = xv * sWih0[20 + c] + sb0[20 + c];
    float gg = xv * sWih0[40 + c] + sb0[40 + c];
    float go = xv * sWih0[60 + c] + sb0[60 + c];
#pragma unroll
    for (int k = 0; k < 20; ++k){
      float h = hp[k];
      gi += h * sWhh0[c*20 + k];
      gf += h * sWhh0[(20 + c)*20 + k];
      gg += h * sWhh0[(40 + c)*20 + k];
      go += h * sWhh0[(60 + c)*20 + k];
    }
    float c0v = Lc[b*20 + c];
    float cn = sigf(gf) * c0v + sigf(gi) * tanhf(gg);
    float hn = sigf(go) * tanhf(cn);
    out_hn[b*20 + c] = hn;
    out_cn[b*20 + c] = cn;
    h0n[c] = hn;
  }
  float hp1[20];
#pragma unroll
  for (int c = 0; c < 20; ++c) hp1[c] = Lh[92160 + b*20 + c];
  float lacc = sbl;
#pragma unroll
  for (int c = 0; c < 20; ++c){
    float gi = sb1[c], gf = sb1[20+c], gg = sb1[40+c], go = sb1[60+c];
#pragma unroll
    for (int k = 0; k < 20; ++k){
      float a0 = h0n[k], a1 = hp1[k];
      gi += a0 * sWih1[c*20 + k]      + a1 * sWhh1[c*20 + k];
      gf += a0 * sWih1[(20+c)*20 + k] + a1 * sWhh1[(20+c)*20 + k];
      gg += a0 * sWih1[(40+c)*20 + k] + a1 * sWhh1[(40+c)*20 + k];
      go += a0 * sWih1[(60+c)*20 + k] + a1 * sWhh1[(60+c)*20 + k];
    }
    float c0v = Lc[92160 + b*20 + c];
    float cn = sigf(gf) * c0v + sigf(gi) * tanhf(gg);
    float hn = sigf(go) * tanhf(cn);
    out_hn[92160 + b*20 + c] = hn;
    out_cn[92160 + b*20 + c] = cn;
    lacc += hn * sWl[c];
  }
  lp[b] = lacc * 0.1f;
}

// ---------------- mean of lp (4608) ----------------
__global__ __launch_bounds__(256) void mean_kernel(
    const float* __restrict__ lp, float* __restrict__ meanout)
{
  __shared__ float red[4];
  int tid = threadIdx.x;
  float s = 0.f;
  for (int i = tid; i < KD; i += 256) s += lp[i];
  for (int off = 32; off; off >>= 1) s += __shfl_down(s, off, 64);
  if ((tid & 63) == 0) red[tid >> 6] = s;
  __syncthreads();
  if (tid == 0) meanout[0] = (red[0]+red[1]+red[2]+red[3]) * (1.0f/4608.0f);
}

// ---------------- L[i][j] = max(Lb[i][j], (i==j)? l_i : 0)  (+ bf16 copy) ----
__global__ __launch_bounds__(256) void build_L_kernel(
    float* __restrict__ outL, ushort_t* __restrict__ outLbf,
    const float* __restrict__ Lb,
    const float* __restrict__ lp, const float* __restrict__ meanp)
{
  size_t idx = (size_t)blockIdx.x * 256 + threadIdx.x;   // float4 index
  int i = (int)(idx / 1152);
  int j = (int)(idx % 1152) * 4;
  float li = lp[i] - meanp[0] + 1.0f;
  float4 lb = *(const float4*)&Lb[(size_t)i*KD + j];
  float4 o;
  o.x = fmaxf(lb.x, (j+0 == i) ? li : 0.f);
  o.y = fmaxf(lb.y, (j+1 == i) ? li : 0.f);
  o.z = fmaxf(lb.z, (j+2 == i) ? li : 0.f);
  o.w = fmaxf(lb.w, (j+3 == i) ? li : 0.f);
  *(float4*)&outL[(size_t)i*KD + j] = o;
  if (outLbf){
    ushort_t b0 = cvt_bf16(o.x), b1 = cvt_bf16(o.y), b2 = cvt_bf16(o.z), b3 = cvt_bf16(o.w);
    unsigned int p0 = (unsigned int)b0 | ((unsigned int)b1 << 16);
    unsigned int p1 = (unsigned int)b2 | ((unsigned int)b3 << 16);
    *(uint2*)&outLbf[(size_t)i*KD + j] = make_uint2(p0, p1);
  }
}

// ---------------- B += M (elementwise, float4) ----------------
__global__ __launch_bounds__(256) void add_kernel(
    float* __restrict__ B, const float* __restrict__ M)
{
  size_t i = ((size_t)blockIdx.x * 256 + threadIdx.x) * 4;
  float4 b = *(const float4*)(B + i);
  float4 m = *(const float4*)(M + i);
  b.x += m.x; b.y += m.y; b.z += m.z; b.w += m.w;
  *(float4*)(B + i) = b;
}

// ---------------- Cholesky: factor 64x64 diag block + invert it ----------------
__global__ __launch_bounds__(256) void chol_factor(
    float* __restrict__ C, float* __restrict__ invLg, int kb)
{
  __shared__ float T[64][65];
  __shared__ float W[64][65];
  const int tid = threadIdx.x;
  const int base = kb * 64;
  for (int t = tid; t < 4096; t += 256)
    T[t>>6][t&63] = C[(size_t)(base + (t>>6))*512 + base + (t&63)];
  __syncthreads();
  const int i = tid & 63, q = tid >> 6;
  for (int j = 0; j < 64; ++j){
    float dj = sqrtf(T[j][j]);
    __syncthreads();
    if (q == 0){
      if (i == j) T[j][j] = dj;
      else if (i > j) T[i][j] /= dj;
    }
    __syncthreads();
    if (i > j){
      float lij = T[i][j];
      for (int jj = j+1+q; jj <= i; jj += 4)
        T[i][jj] -= lij * T[jj][j];
    }
    __syncthreads();
  }
  if (q == 0){
    const int j = i;
    for (int r = 0; r < j; ++r) W[r][j] = 0.f;
    W[j][j] = 1.0f / T[j][j];
    for (int r = j+1; r < 64; ++r){
      float ssum = 0.f;
      for (int k = j; k < r; ++k) ssum += T[r][k] * W[k][j];
      W[r][j] = -ssum / T[r][r];
    }
  }
  __syncthreads();
  for (int t = tid; t < 4096; t += 256){
    int r = t >> 6, c = t & 63;
    C[(size_t)(base + r)*512 + base + c] = T[r][c];
    invLg[kb*4096 + t] = W[r][c];
  }
}

// ---------------- panel solve: L21 = C21 @ invL^T (in-place) ----------------
__global__ __launch_bounds__(256) void chol_trsm(
    float* __restrict__ C, const float* __restrict__ invLg, int kb)
{
  __shared__ float Ts[64][65];
  __shared__ float Ws[64][65];
  const int tid = threadIdx.x;
  const int r0 = 64*(kb+1) + blockIdx.x * 64;
  const int cb = kb * 64;
  for (int t = tid; t < 1024; t += 256){
    int r = t >> 4, qd = (t & 15) << 2;
    float4 v = *(const float4*)&C[(size_t)(r0+r)*512 + cb + qd];
    Ts[r][qd]=v.x; Ts[r][qd+1]=v.y; Ts[r][qd+2]=v.z; Ts[r][qd+3]=v.w;
    float4 w = *(const float4*)&invLg[kb*4096 + r*64 + qd];
    Ws[r][qd]=w.x; Ws[r][qd+1]=w.y; Ws[r][qd+2]=w.z; Ws[r][qd+3]=w.w;
  }
  __syncthreads();
  const int tx = tid & 15, ty = tid >> 4;
  float acc[4][4] = {};
#pragma unroll 8
  for (int k = 0; k < 64; ++k){
    float a_[4], b_[4];
#pragma unroll
    for (int i=0;i<4;i++){ a_[i] = Ts[(ty<<2)+i][k]; b_[i] = Ws[(tx<<2)+i][k]; }
#pragma unroll
    for (int i=0;i<4;i++)
#pragma unroll
      for (int j=0;j<4;j++)
        acc[i][j] += a_[i]*b_[j];
  }
#pragma unroll
  for (int i=0;i<4;i++)
#pragma unroll
    for (int j=0;j<4;j++)
      C[(size_t)(r0+(ty<<2)+i)*512 + cb + (tx<<2)+j] = acc[i][j];
}

// ---------------- trailing update: C22 -= Lp @ Lp^T (lower tiles only) ------
__global__ __launch_bounds__(256) void chol_syrk(float* __restrict__ C, int kb)
{
  if (blockIdx.y > blockIdx.x) return;
  __shared__ float Ar[64][65];
  __shared__ float Ac[64][65];
  const int tid = threadIdx.x;
  const int base = 64*(kb+1);
  const int r0 = base + blockIdx.x * 64, c0 = base + blockIdx.y * 64;
  const int cb = kb * 64;
  for (int t = tid; t < 1024; t += 256){
    int r = t >> 4, qd = (t & 15) << 2;
    float4 v = *(const float4*)&C[(size_t)(r0+r)*512 + cb + qd];
    Ar[r][qd]=v.x; Ar[r][qd+1]=v.y; Ar[r][qd+2]=v.z; Ar[r][qd+3]=v.w;
    float4 w = *(const float4*)&C[(size_t)(c0+r)*512 + cb + qd];
    Ac[r][qd]=w.x; Ac[r][qd+1]=w.y; Ac[r][qd+2]=w.z; Ac[r][qd+3]=w.w;
  }
  __syncthreads();
  const int tx = tid & 15, ty = tid >> 4;
  float acc[4][4] = {};
#pragma unroll 8
  for (int k = 0; k < 64; ++k){
    float a_[4], b_[4];
#pragma unroll
    for (int i=0;i<4;i++){ a_[i] = Ar[(ty<<2)+i][k]; b_[i] = Ac[(tx<<2)+i][k]; }
#pragma unroll
    for (int i=0;i<4;i++)
#pragma unroll
      for (int j=0;j<4;j++)
        acc[i][j] += a_[i]*b_[j];
  }
#pragma unroll
  for (int i=0;i<4;i++)
#pragma unroll
    for (int j=0;j<4;j++){
      size_t o = (size_t)(r0+(ty<<2)+i)*512 + c0 + (tx<<2)+j;
      C[o] -= acc[i][j];
    }
}

// ---------------- Q panel back-substitution ----------------
__global__ __launch_bounds__(256) void panel_q(
    float* __restrict__ Q, const float* __restrict__ B,
    const float* __restrict__ Lc, const float* __restrict__ invLg, int jb)
{
  __shared__ float Qs[16][64];
  __shared__ float Rs[16][68];
  __shared__ float Ts[64][65];
  __shared__ float Ws[64][65];
  const int tid = threadIdx.x;
  const int tx = tid & 15, ty = tid >> 4;
  const int r0 = blockIdx.x * 64;
  const int cb = jb * 64;
  for (int t = tid; t < 4096; t += 256)
    Ws[t>>6][t&63] = invLg[jb*4096 + t];
  float acc[4][4] = {};
  const int lr = tid >> 2, lk = (tid & 3) << 2;
  for (int k0 = 0; k0 < cb; k0 += 16){
    float4 qv = *(const float4*)&Q[(size_t)(r0+lr)*512 + k0 + lk];
    Qs[lk+0][lr]=qv.x; Qs[lk+1][lr]=qv.y; Qs[lk+2][lr]=qv.z; Qs[lk+3][lr]=qv.w;
    float4 rv = *(const float4*)&Lc[(size_t)(cb+lr)*512 + k0 + lk];
    Rs[lk+0][lr]=rv.x; Rs[lk+1][lr]=rv.y; Rs[lk+2][lr]=rv.z; Rs[lk+3][lr]=rv.w;
    __syncthreads();
#pragma unroll
    for (int k = 0; k < 16; ++k){
      float4 a4 = *(const float4*)&Qs[k][ty<<2];
      float av[4] = {a4.x,a4.y,a4.z,a4.w};
      float bv[4];
#pragma unroll
      for (int j=0;j<4;j++) bv[j] = Rs[k][(tx<<2)+j];
#pragma unroll
      for (int i=0;i<4;i++)
#pragma unroll
        for (int j=0;j<4;j++)
          acc[i][j] += av[i]*bv[j];
    }
    __syncthreads();
  }
#pragma unroll
  for (int i=0;i<4;i++){
    int r = (ty<<2)+i;
#pragma unroll
    for (int j=0;j<4;j++){
      int c = (tx<<2)+j;
      Ts[r][c] = B[(size_t)(r0+r)*512 + cb + c] - acc[i][j];
    }
  }
  __syncthreads();
  float acc2[4][4] = {};
#pragma unroll 8
  for (int k = 0; k < 64; ++k){
    float a_[4], b_[4];
#pragma unroll
    for (int i=0;i<4;i++){ a_[i] = Ts[(ty<<2)+i][k]; b_[i] = Ws[(tx<<2)+i][k]; }
#pragma unroll
    for (int i=0;i<4;i++)
#pragma unroll
      for (int j=0;j<4;j++)
        acc2[i][j] += a_[i]*b_[j];
  }
#pragma unroll
  for (int i=0;i<4;i++)
#pragma unroll
    for (int j=0;j<4;j++)
      Q[(size_t)(r0+(ty<<2)+i)*512 + cb + (tx<<2)+j] = acc2[i][j];
}

extern "C" void kernel_launch(void* const* d_in, const int* in_sizes, int n_in,
                              void* d_out, int out_size, void* d_ws, size_t ws_size,
                              hipStream_t stream) {
  const float* e      = (const float*)d_in[0];
  const float* e_grad = (const float*)d_in[1];
  const float* s      = (const float*)d_in[2];
  const float* s_grad = (const float*)d_in[3];
  const float* L_h0   = (const float*)d_in[4];
  const float* L_c0   = (const float*)d_in[5];
  const float* L_before = (const float*)d_in[6];
  const float* W_ih0  = (const float*)d_in[7];
  const float* W_hh0  = (const float*)d_in[8];
  const float* b_ih0  = (const float*)d_in[9];
  const float* b_hh0  = (const float*)d_in[10];
  const float* W_ih1  = (const float*)d_in[11];
  const float* W_hh1  = (const float*)d_in[12];
  const float* b_ih1  = (const float*)d_in[13];
  const float* b_hh1  = (const float*)d_in[14];
  const float* Wl     = (const float*)d_in[15];
  const float* bl     = (const float*)d_in[16];
  const float* e_lr   = (const float*)d_in[17];
  const float* s_lr   = (const float*)d_in[18];

  float* out = (float*)d_out;
  float* out_e  = out + OFF_E;
  float* out_s  = out + OFF_S;
  float* out_L  = out + OFF_L;
  float* out_hn = out + OFF_HN;
  float* out_cn = out + OFF_CN;

  // workspace layout (floats)
  float* ws   = (float*)d_ws;
  float* M    = ws;                 // (4608x512)  M = s^T
  float* Bb   = ws + 2359296;       // Mg -> LG -> B
  float* G    = ws + 4718592;       // G -> Q
  float* Abuf = ws + 7077888;       // A / A2
  float* Asym = ws + 7340032;
  float* Cb   = ws + 7602176;       // B^T B -> Cholesky factor (lower)
  float* invL = ws + 7864320;       // 8 x 64x64 inverse diag blocks
  float* xb   = ws + 7897088;
  float* lp   = ws + 7901696;
  float* meanb= ws + 7906304;
  // bf16 extension region (for MFMA path): needs ws_size >= 78,812,160 bytes
  ushort_t* Lbf = (ushort_t*)(ws + 7906560);              // 4608x4608 bf16
  ushort_t* Gt  = (ushort_t*)(ws + 7906560 + 10616832);   // 512x4608 bf16 (G^T)
  const bool use_mfma = ws_size >= (size_t)(7906560 + 10616832 + 1179648) * 4;

  // 1. new_e
  new_e_kernel<<<16384, 256, 0, stream>>>(out_e, e, e_grad, e_lr);
  // 2. M = s^T ; Mg = -s_lr * s_grad^T
  transpose_k<<<dim3(144,16), dim3(32,8), 0, stream>>>(M, s, 512, KD, nullptr, 1.0f);
  transpose_k<<<dim3(144,16), dim3(32,8), 0, stream>>>(Bb, s_grad, 512, KD, s_lr, -1.0f);
  // 3. A = M^T Mg ; Asym
  hipMemsetAsync(Abuf, 0, 262144*sizeof(float), stream);
  gemm_tn_splitk<<<dim3(8,8,9), 256, 0, stream>>>(Abuf, M, Bb, 512);
  sym_kernel<<<1024, 256, 0, stream>>>(Asym, Abuf);
  // 4. G = Mg - M @ Asym
  gemm_nn<64><<<dim3(72,8), 256, 0, stream>>>(G, M, Asym, Bb, -1.f, 1.f, 512, 512);
  // 5. x = clip(log(|rownorm2|)/10, -1, 1)
  rowsq_kernel<<<1152, 256, 0, stream>>>(G, xb);
  // 5b. Gt = bf16(G^T) for MFMA B-operand
  if (use_mfma)
    transpose_cvt_bf16<<<dim3(16,144), dim3(32,8), 0, stream>>>(Gt, G, KD, 512);
  // 6. LSTM
  lstm_kernel<<<18, 256, 0, stream>>>(xb, L_h0, L_c0, W_ih0, W_hh0, b_ih0, b_hh0,
                                      W_ih1, W_hh1, b_ih1, b_hh1, Wl, bl,
                                      out_hn, out_cn, lp);
  mean_kernel<<<1, 256, 0, stream>>>(lp, meanb);
  // 7. L = max(diag(l), L_before)  (fp32 output + bf16 copy)
  build_L_kernel<<<20736, 256, 0, stream>>>(out_L, use_mfma ? Lbf : nullptr,
                                            L_before, lp, meanb);
  // 8. LG = L @ G   (21.7 GFLOP -> bf16 MFMA)
  if (use_mfma)
    gemm_LG_mfma<<<576, 256, 0, stream>>>(Bb, Lbf, Gt);
  else
    gemm_nn<128><<<dim3(72,4), 256, 0, stream>>>(Bb, out_L, G, nullptr, 1.f, 0.f, KD, KD);
  // 9. A2 = M^T LG ; A2sym
  hipMemsetAsync(Abuf, 0, 262144*sizeof(float), stream);
  gemm_tn_splitk<<<dim3(8,8,9), 256, 0, stream>>>(Abuf, M, Bb, 512);
  sym_kernel<<<1024, 256, 0, stream>>>(Asym, Abuf);
  // 10. B = M + LG - M @ A2sym
  add_kernel<<<2304, 256, 0, stream>>>(Bb, M);
  gemm_nn<64><<<dim3(72,8), 256, 0, stream>>>(Bb, M, Asym, Bb, -1.f, 1.f, 512, 512);
  // 11. C = B^T B
  hipMemsetAsync(Cb, 0, 262144*sizeof(float), stream);
  gemm_tn_splitk<<<dim3(8,8,9), 256, 0, stream>>>(Cb, Bb, Bb, 512);
  // 12. blocked Cholesky C = Lc Lc^T (NB=64)
  for (int kb = 0; kb < 8; ++kb){
    chol_factor<<<1, 256, 0, stream>>>(Cb, invL, kb);
    int rem = 7 - kb;
    if (rem > 0){
      chol_trsm<<<rem, 256, 0, stream>>>(Cb, invL, kb);
      chol_syrk<<<dim3(rem, rem), 256, 0, stream>>>(Cb, kb);
    }
  }
  // 13. Q = B R^{-1} via block back-substitution (Q into G buffer)
  for (int jb = 0; jb < 8; ++jb)
    panel_q<<<72, 256, 0, stream>>>(G, Bb, Cb, invL, jb);
  // 14. new_s = Q^T
  transpose_k<<<dim3(16,144), dim3(32,8), 0, stream>>>(out_s, G, KD, 512, nullptr, 1.0f);
}